// Round 1
// baseline (39.305 us; speedup 1.0000x reference)
//
#include <hip/hip_runtime.h>
#include <math.h>

static constexpr int   BATCH = 256;
static constexpr int   DIM   = 256;
static constexpr int   NSV   = 512;   // P == Q == 512
static constexpr float GMA   = 0.1f;
static constexpr int   NB    = 2;     // batch rows per block
static constexpr int   NT    = 512;   // threads per block (8 waves)

__global__ __launch_bounds__(NT)
void rbf_svm_fused(const float* __restrict__ x,
                   const float* __restrict__ sv1,
                   const float* __restrict__ sv0,
                   const float* __restrict__ a1,
                   const float* __restrict__ a0,
                   float* __restrict__ out)
{
    __shared__ float  x2[NB][DIM];
    __shared__ float4 wred[NT / 64];

    const int t     = threadIdx.x;
    const int bbase = blockIdx.x * NB;

    // stage 2*x rows: NB*DIM = 512 elements, one per thread
    {
        const int jb = t >> 8;          // t / DIM
        const int jd = t & (DIM - 1);   // t % DIM
        x2[jb][jd] = 2.0f * x[(bbase + jb) * DIM + jd];
    }
    __syncthreads();

    const float4* __restrict__ r1 = reinterpret_cast<const float4*>(sv1 + (size_t)t * DIM);
    const float4* __restrict__ r0 = reinterpret_cast<const float4*>(sv0 + (size_t)t * DIM);
    const float4* xa = reinterpret_cast<const float4*>(x2[0]);
    const float4* xb = reinterpret_cast<const float4*>(x2[1]);

    // acc{set}{batch}:  Σ_d s[d]*(s[d] - 2x[d])
    float acc1a = 0.f, acc1b = 0.f, acc0a = 0.f, acc0b = 0.f;

    #pragma unroll 4
    for (int k = 0; k < DIM / 4; ++k) {
        const float4 v1 = r1[k];
        const float4 v0 = r0[k];
        const float4 pa = xa[k];
        const float4 pb = xb[k];

        acc1a = fmaf(v1.x, v1.x - pa.x, acc1a);
        acc1a = fmaf(v1.y, v1.y - pa.y, acc1a);
        acc1a = fmaf(v1.z, v1.z - pa.z, acc1a);
        acc1a = fmaf(v1.w, v1.w - pa.w, acc1a);

        acc1b = fmaf(v1.x, v1.x - pb.x, acc1b);
        acc1b = fmaf(v1.y, v1.y - pb.y, acc1b);
        acc1b = fmaf(v1.z, v1.z - pb.z, acc1b);
        acc1b = fmaf(v1.w, v1.w - pb.w, acc1b);

        acc0a = fmaf(v0.x, v0.x - pa.x, acc0a);
        acc0a = fmaf(v0.y, v0.y - pa.y, acc0a);
        acc0a = fmaf(v0.z, v0.z - pa.z, acc0a);
        acc0a = fmaf(v0.w, v0.w - pa.w, acc0a);

        acc0b = fmaf(v0.x, v0.x - pb.x, acc0b);
        acc0b = fmaf(v0.y, v0.y - pb.y, acc0b);
        acc0b = fmaf(v0.z, v0.z - pb.z, acc0b);
        acc0b = fmaf(v0.w, v0.w - pb.w, acc0b);
    }

    const float la1 = logf(a1[t]);
    const float la0 = logf(a0[t]);

    // score = g*acc - log(alpha);  pack as (set1_b0, set0_b0, set1_b1, set0_b1)
    float4 sc;
    sc.x = GMA * acc1a - la1;
    sc.y = GMA * acc0a - la0;
    sc.z = GMA * acc1b - la1;
    sc.w = GMA * acc0b - la0;

    // ---- block-wide LSE over the NT=512 scores, 4 reductions at once ----
    // 1) max reduce
    float4 m = sc;
    #pragma unroll
    for (int off = 32; off > 0; off >>= 1) {
        m.x = fmaxf(m.x, __shfl_xor(m.x, off));
        m.y = fmaxf(m.y, __shfl_xor(m.y, off));
        m.z = fmaxf(m.z, __shfl_xor(m.z, off));
        m.w = fmaxf(m.w, __shfl_xor(m.w, off));
    }
    if ((t & 63) == 0) wred[t >> 6] = m;
    __syncthreads();
    float4 M = wred[0];
    #pragma unroll
    for (int i = 1; i < NT / 64; ++i) {
        M.x = fmaxf(M.x, wred[i].x);
        M.y = fmaxf(M.y, wred[i].y);
        M.z = fmaxf(M.z, wred[i].z);
        M.w = fmaxf(M.w, wred[i].w);
    }
    __syncthreads();   // wred reused below

    // 2) sum of exp
    float4 e;
    e.x = __expf(sc.x - M.x);
    e.y = __expf(sc.y - M.y);
    e.z = __expf(sc.z - M.z);
    e.w = __expf(sc.w - M.w);
    #pragma unroll
    for (int off = 32; off > 0; off >>= 1) {
        e.x += __shfl_xor(e.x, off);
        e.y += __shfl_xor(e.y, off);
        e.z += __shfl_xor(e.z, off);
        e.w += __shfl_xor(e.w, off);
    }
    if ((t & 63) == 0) wred[t >> 6] = e;
    __syncthreads();
    if (t == 0) {
        float4 S = wred[0];
        #pragma unroll
        for (int i = 1; i < NT / 64; ++i) {
            S.x += wred[i].x;
            S.y += wred[i].y;
            S.z += wred[i].z;
            S.w += wred[i].w;
        }
        // out[b] = lse(set0) - lse(set1)
        out[bbase + 0] = (M.y + logf(S.y)) - (M.x + logf(S.x));
        out[bbase + 1] = (M.w + logf(S.w)) - (M.z + logf(S.z));
    }
}

extern "C" void kernel_launch(void* const* d_in, const int* in_sizes, int n_in,
                              void* d_out, int out_size, void* d_ws, size_t ws_size,
                              hipStream_t stream) {
    const float* x   = (const float*)d_in[0];
    const float* sv1 = (const float*)d_in[1];
    const float* sv0 = (const float*)d_in[2];
    const float* a1  = (const float*)d_in[3];
    const float* a0  = (const float*)d_in[4];
    float* out = (float*)d_out;

    rbf_svm_fused<<<BATCH / NB, NT, 0, stream>>>(x, sv1, sv0, a1, a0, out);
}

// Round 2
// 15.502 us; speedup vs baseline: 2.5354x; 2.5354x over previous
//
#include <hip/hip_runtime.h>
#include <math.h>

static constexpr int   B    = 256;   // batch
static constexpr int   D    = 256;   // feature dim
static constexpr int   NSV  = 512;   // P == Q
static constexpr int   NB   = 4;     // batches per block
static constexpr int   RG   = 4;     // row-groups (SV split)
static constexpr int   RPS  = NSV / RG;   // 128 rows per set per block
static constexpr int   RPB  = 2 * RPS;    // 256 tile rows (set1 then set0)
static constexpr int   NT   = 256;        // threads per block (4 waves)
static constexpr int   KC   = 64;         // k-chunk (floats)
static constexpr int   NCH  = D / KC;     // 4 chunks
static constexpr float G    = 0.1f;
static constexpr float CSH  = 26.0f;      // fixed LSE shift; cancels in LSE0-LSE1

__device__ __forceinline__ void gld16(const void* g, void* l) {
    __builtin_amdgcn_global_load_lds((__attribute__((address_space(1))) void*)g,
                                     (__attribute__((address_space(3))) void*)l,
                                     16, 0, 0);
}

// Partial sums: block (rg, bg) covers SV rows [rg*128, rg*128+128) of BOTH sets
// for batches [bg*4, bg*4+4). Writes sum_{rows} exp(score - CSH) per (set, batch).
__global__ __launch_bounds__(NT)
void k_partial(const float* __restrict__ x,
               const float* __restrict__ sv1,
               const float* __restrict__ sv0,
               const float* __restrict__ a1,
               const float* __restrict__ a0,
               float* __restrict__ ws)
{
    __shared__ float tile[2][RPB * KC];   // 2 x 64 KiB double buffer
    __shared__ float red[4][NB];

    const int t     = threadIdx.x;
    const int rg    = blockIdx.x;
    const int bbase = blockIdx.y * NB;

    float ssq = 0.f, d0 = 0.f, d1 = 0.f, d2 = 0.f, d3 = 0.f;
    const float* xb = x + (size_t)bbase * D;

    #pragma unroll
    for (int c = 0; c < NCH + 1; ++c) {
        if (c < NCH) {
            // stage chunk c into buffer c&1 (linear LDS dest, XOR-swizzled global src)
            #pragma unroll
            for (int i = 0; i < 16; ++i) {
                const int f = i * NT + t;      // 0..4095 f4-slots
                const int r = f >> 4;          // tile row 0..255
                const int p = f & 15;          // physical f4 slot in row
                const int q = p ^ (r & 7);     // logical slot (involution)
                const float* src = (r < RPS)
                    ? (sv1 + (size_t)(rg * RPS + r) * D)
                    : (sv0 + (size_t)(rg * RPS + (r - RPS)) * D);
                src += c * KC + q * 4;
                gld16(src, &tile[c & 1][f * 4]);
            }
        }
        if (c == 0) continue;
        const int cc = c - 1;                 // compute chunk cc from buffer cc&1

        if (c < NCH) asm volatile("s_waitcnt vmcnt(16)" ::: "memory");
        else         asm volatile("s_waitcnt vmcnt(0)"  ::: "memory");
        __builtin_amdgcn_s_barrier();
        __builtin_amdgcn_sched_barrier(0);

        const float4* tf = reinterpret_cast<const float4*>(&tile[cc & 1][0]);
        const float*  xc = xb + cc * KC;
        #pragma unroll
        for (int kk = 0; kk < 16; ++kk) {
            const int p = kk ^ (t & 7);                 // de-swizzle
            const float4 s4  = tf[(t << 4) + p];        // this thread's row
            const float4 xv0 = *reinterpret_cast<const float4*>(xc + 0 * D + kk * 4);
            const float4 xv1 = *reinterpret_cast<const float4*>(xc + 1 * D + kk * 4);
            const float4 xv2 = *reinterpret_cast<const float4*>(xc + 2 * D + kk * 4);
            const float4 xv3 = *reinterpret_cast<const float4*>(xc + 3 * D + kk * 4);
            ssq = fmaf(s4.x, s4.x, ssq);
            ssq = fmaf(s4.y, s4.y, ssq);
            ssq = fmaf(s4.z, s4.z, ssq);
            ssq = fmaf(s4.w, s4.w, ssq);
            d0 = fmaf(s4.x, xv0.x, d0); d0 = fmaf(s4.y, xv0.y, d0);
            d0 = fmaf(s4.z, xv0.z, d0); d0 = fmaf(s4.w, xv0.w, d0);
            d1 = fmaf(s4.x, xv1.x, d1); d1 = fmaf(s4.y, xv1.y, d1);
            d1 = fmaf(s4.z, xv1.z, d1); d1 = fmaf(s4.w, xv1.w, d1);
            d2 = fmaf(s4.x, xv2.x, d2); d2 = fmaf(s4.y, xv2.y, d2);
            d2 = fmaf(s4.z, xv2.z, d2); d2 = fmaf(s4.w, xv2.w, d2);
            d3 = fmaf(s4.x, xv3.x, d3); d3 = fmaf(s4.y, xv3.y, d3);
            d3 = fmaf(s4.z, xv3.z, d3); d3 = fmaf(s4.w, xv3.w, d3);
        }
        __builtin_amdgcn_sched_barrier(0);
        __builtin_amdgcn_s_barrier();
        __builtin_amdgcn_sched_barrier(0);
    }

    // score = g*(||s||^2 - 2 s.x) - log(alpha);  e = exp(score - CSH)
    const int   lane = t & 63;
    const int   wv   = t >> 6;               // waves 0,1 = set1; 2,3 = set0
    const int   rloc = t & (RPS - 1);
    const float av   = (t < RPS) ? a1[rg * RPS + rloc] : a0[rg * RPS + rloc];
    const float lal  = logf(av);

    float e0 = __expf(G * (ssq - 2.f * d0) - lal - CSH);
    float e1 = __expf(G * (ssq - 2.f * d1) - lal - CSH);
    float e2 = __expf(G * (ssq - 2.f * d2) - lal - CSH);
    float e3 = __expf(G * (ssq - 2.f * d3) - lal - CSH);

    #pragma unroll
    for (int off = 32; off > 0; off >>= 1) {
        e0 += __shfl_xor(e0, off);
        e1 += __shfl_xor(e1, off);
        e2 += __shfl_xor(e2, off);
        e3 += __shfl_xor(e3, off);
    }
    if (lane == 0) { red[wv][0] = e0; red[wv][1] = e1; red[wv][2] = e2; red[wv][3] = e3; }
    __syncthreads();
    if (t < 8) {
        const int s = t >> 2;                 // 0 = set1, 1 = set0
        const int b = t & 3;
        const float S = red[s * 2][b] + red[s * 2 + 1][b];
        ws[s * (RG * B) + rg * B + bbase + b] = S;
    }
}

// Combine row-group partials: out[b] = log(S0) - log(S1)  (CSH cancels)
__global__ __launch_bounds__(B)
void k_final(const float* __restrict__ ws, float* __restrict__ out)
{
    const int b = threadIdx.x;
    float S1 = 0.f, S0 = 0.f;
    #pragma unroll
    for (int rg = 0; rg < RG; ++rg) {
        S1 += ws[rg * B + b];
        S0 += ws[RG * B + rg * B + b];
    }
    out[b] = logf(S0) - logf(S1);
}

extern "C" void kernel_launch(void* const* d_in, const int* in_sizes, int n_in,
                              void* d_out, int out_size, void* d_ws, size_t ws_size,
                              hipStream_t stream) {
    const float* x   = (const float*)d_in[0];
    const float* sv1 = (const float*)d_in[1];
    const float* sv0 = (const float*)d_in[2];
    const float* a1  = (const float*)d_in[3];
    const float* a0  = (const float*)d_in[4];
    float* ws  = (float*)d_ws;
    float* out = (float*)d_out;

    dim3 g1(RG, B / NB);   // 4 x 64 = 256 blocks
    k_partial<<<g1, NT, 0, stream>>>(x, sv1, sv0, a1, a0, ws);
    k_final<<<1, B, 0, stream>>>(ws, out);
}